// Round 10
// baseline (849.977 us; speedup 1.0000x reference)
//
#include <hip/hip_runtime.h>

// SocialPoolingLayer: fused edge-MLP (relu(pair@W1+b1)@W2+b2, sigmoid gate, elemwise
// product) + scatter-mean by src node.
// Round 10: ONE persistent kernel. R5-R9 showed the 5-node dependent chain costs
// ~150us of tail vs ~35us of actual work. Grid = 256 CUs x 4 blocks, all co-resident
// by construction (launch_bounds(256,4), 18.9KB LDS, regs<=128), so software grid
// barriers (monotonic counter, AGENT-scope acq/rel atomics -> cross-XCD L2
// writeback/invalidate) are deadlock-free. Phases: prep -> hist -> scan(2) ->
// scatter -> R9's MLP body (verbatim, tile-strided). Scatter reads bsum[s>>8]
// directly (drops the per-block LDS prefix + one barrier). Workspace = exactly the
// proven 10,034,048B extent (bsum 256->240 ints pays for the 64B barrier block).

typedef unsigned short ushort_t;
typedef __attribute__((ext_vector_type(8))) short     bf16x8;   // 8 bf16 = 4 VGPRs
typedef __attribute__((ext_vector_type(8))) unsigned short u16x8;
typedef __attribute__((ext_vector_type(4))) float     f32x4;

constexpr int D        = 64;
constexpr int TILE     = 64;     // edges per tile (4 waves x 16 edges)
constexpr int BLOCK    = 256;
constexpr int NBLK     = 1024;   // 4 blocks/CU x 256 CUs, provably co-resident
constexpr int NFRAG    = 32;     // 16 (W1) + 8 (W2) + 8 (W2@Wg) B-fragments
constexpr int SLAB_B   = 4352;   // per-wave slab: 16 rows x 272 B
constexpr int PAIR_STR = 136;    // pair row stride (bf16): 272 B
constexpr int H_STR    = 72;     // h row stride (bf16): 144 B

static __device__ __forceinline__ ushort_t f2bf(float f) {
    union { float f; unsigned int u; } v; v.f = f;
    const unsigned int r = v.u + 0x7FFFu + ((v.u >> 16) & 1u);   // RNE
    return (ushort_t)(r >> 16);
}

// Device-wide barrier: monotonic arrival counter, no reset. Safe because all NBLK
// blocks are co-resident. AGENT-scope release/acquire give cross-XCD visibility
// (L2 writeback on release, invalidate on acquire).
static __device__ __forceinline__ void grid_sync(unsigned* bar, unsigned target) {
    __syncthreads();
    if (threadIdx.x == 0) {
        __hip_atomic_fetch_add(bar, 1u, __ATOMIC_ACQ_REL, __HIP_MEMORY_SCOPE_AGENT);
        while (__hip_atomic_load(bar, __ATOMIC_ACQUIRE, __HIP_MEMORY_SCOPE_AGENT) < target)
            __builtin_amdgcn_s_sleep(8);
    }
    __syncthreads();
}

__global__ __launch_bounds__(BLOCK, 4)
void uber_kernel(const float* __restrict__ W1, const float* __restrict__ W2,
                 const float* __restrict__ Wg, const float* __restrict__ pb1,
                 const float* __restrict__ pb2, const float* __restrict__ pbg,
                 const float* __restrict__ emb, const int* __restrict__ ei,
                 unsigned* __restrict__ bar, int* __restrict__ cnt,
                 int* __restrict__ off, int* __restrict__ bsum,
                 unsigned* __restrict__ sorted, float* __restrict__ bgp,
                 ushort_t* __restrict__ wpack, ushort_t* __restrict__ emb_bf,
                 float* __restrict__ summed,
                 int N, int E, int total_emb, int ntiles, int nsb)
{
    __shared__ char  slab[4][SLAB_B];    // 17408 B (phase 4)
    __shared__ int   si[256];            // scan scratch (phases 2a/2b)
    __shared__ int   srcIds[TILE];
    __shared__ float rcS[TILE];

    const int tid = threadIdx.x;
    const int bid = blockIdx.x;
    const int gid = bid * BLOCK + tid;
    constexpr int G = NBLK * BLOCK;      // 262144 threads

    // ================= phase 0: pack + W2Wg + bg' + emb->bf16 + zeroing =========
    // Weight fragment layout (verified R3): frag f, lane l, elem j -> W[k][n],
    // k = kc*32 + (l>>4)*8 + j, n = nt*16 + (l&15).
    for (int t = gid; t < NFRAG * 512; t += G) {
        const int f = t >> 9;
        const int l = (t >> 3) & 63;
        const int j = t & 7;
        const int k = ((f < 16) ? (f & 3) : ((f - 16) & 1)) * 32 + (l >> 4) * 8 + j;
        const int n = ((f < 16) ? (f >> 2) : (((f & 7)) >> 1)) * 16 + (l & 15);
        float v;
        if (f < 16)      v = W1[k * 64 + n];
        else if (f < 24) v = W2[k * 64 + n];
        else {                                   // (W2@Wg)[k][n]
            float s = 0.f;
            const float* wr = W2 + k * 64;
#pragma unroll 8
            for (int m = 0; m < 64; ++m) s += wr[m] * Wg[m * 64 + n];
            v = s;
        }
        wpack[t] = f2bf(v);
    }
    if (gid < 64) {                              // bg' = b2@Wg + bg (fp32)
        float s = pbg[gid];
#pragma unroll 8
        for (int m = 0; m < 64; ++m) s += pb2[m] * Wg[m * 64 + gid];
        bgp[gid] = s;
    }
    for (int i = gid; i < N; i += G) cnt[i] = 0;
    for (int i = gid; i * 8 < total_emb; i += G) {   // node_emb -> bf16
        const int base = i * 8;
        const float4 a = *(const float4*)(emb + base);
        const float4 b = *(const float4*)(emb + base + 4);
        u16x8 p;
        p[0]=f2bf(a.x); p[1]=f2bf(a.y); p[2]=f2bf(a.z); p[3]=f2bf(a.w);
        p[4]=f2bf(b.x); p[5]=f2bf(b.y); p[6]=f2bf(b.z); p[7]=f2bf(b.w);
        *(u16x8*)(emb_bf + base) = p;
    }
    for (int i = gid; i * 4 < total_emb; i += G)     // zero summed
        *(float4*)(summed + i * 4) = (float4){0.f, 0.f, 0.f, 0.f};

    grid_sync(bar, 1u * NBLK);

    // ================= phase 1: edge histogram by src ===========================
    for (int i = gid; i * 4 < E; i += G) {
        const int e = i * 4;
        if (e + 3 < E) {
            const int4 v = *(const int4*)(ei + e);
            atomicAdd(&cnt[v.x], 1); atomicAdd(&cnt[v.y], 1);
            atomicAdd(&cnt[v.z], 1); atomicAdd(&cnt[v.w], 1);
        } else {
            for (int k = e; k < E; ++k) atomicAdd(&cnt[ei[k]], 1);
        }
    }
    grid_sync(bar, 2u * NBLK);

    // ================= phase 2a: per-256-chunk exclusive scan ===================
    if (bid < nsb) {
        const int i = bid * 256 + tid;
        const int x = (i < N) ? cnt[i] : 0;
        si[tid] = x; __syncthreads();
        for (int d = 1; d < 256; d <<= 1) {
            const int v = (tid >= d) ? si[tid - d] : 0;
            __syncthreads();
            si[tid] += v;
            __syncthreads();
        }
        if (i < N) off[i] = si[tid] - x;          // chunk-local exclusive prefix
        if (tid == 255) bsum[bid] = si[255];
    }
    grid_sync(bar, 3u * NBLK);

    // ================= phase 2b: block 0 scans the chunk sums (nsb <= 240) ======
    if (bid == 0) {
        const int x = (tid < nsb) ? bsum[tid] : 0;
        si[tid] = x; __syncthreads();
        for (int d = 1; d < 256; d <<= 1) {
            const int v = (tid >= d) ? si[tid - d] : 0;
            __syncthreads();
            si[tid] += v;
            __syncthreads();
        }
        if (tid < nsb) bsum[tid] = si[tid] - x;   // exclusive chunk base
    }
    grid_sync(bar, 4u * NBLK);

    // ================= phase 3: scatter packed (src<<16)|dst, sorted by src =====
    // off[] doubles as insertion cursor; global slot = bsum[s>>8] + cursor.
    for (int i = gid; i * 4 < E; i += G) {
        const int e = i * 4;
        if (e + 3 < E) {
            const int4 v  = *(const int4*)(ei + e);        // src
            const int4 d4 = *(const int4*)(ei + E + e);    // dst
            sorted[bsum[v.x >> 8] + atomicAdd(&off[v.x], 1)] =
                ((unsigned)v.x << 16) | (unsigned)d4.x;
            sorted[bsum[v.y >> 8] + atomicAdd(&off[v.y], 1)] =
                ((unsigned)v.y << 16) | (unsigned)d4.y;
            sorted[bsum[v.z >> 8] + atomicAdd(&off[v.z], 1)] =
                ((unsigned)v.z << 16) | (unsigned)d4.z;
            sorted[bsum[v.w >> 8] + atomicAdd(&off[v.w], 1)] =
                ((unsigned)v.w << 16) | (unsigned)d4.w;
        } else {
            for (int k = e; k < E; ++k) {
                const int s = ei[k];
                sorted[bsum[s >> 8] + atomicAdd(&off[s], 1)] =
                    ((unsigned)s << 16) | (unsigned)ei[E + k];
            }
        }
    }
    grid_sync(bar, 5u * NBLK);

    // ================= phase 4: fused MFMA MLP + segmented scatter (R9 body) ====
    // Wave w owns slab[w] + srcIds/rcS rows 16w..16w+15 -> barrier-free inside.
    const int w    = tid >> 6;
    const int ln   = tid & 63;
    const int quad = ln >> 4;
    const int cn   = ln & 15;
    ushort_t* pairW = (ushort_t*)slab[w];   // [16][136]
    ushort_t* hW    = (ushort_t*)slab[w];   // [16][72] (overwrites pair after a1 reads)

    for (int tile = bid; tile < ntiles; tile += NBLK) {
        // ---- stage: one packed 4B load -> two 128B row gathers ----
        {
            const int e = tid >> 2, q4 = tid & 3;
            ushort_t* prow = (ushort_t*)&slab[e >> 4][(e & 15) * (PAIR_STR * 2)];
            const int ide = tile * TILE + e;
            if (ide < E) {
                const unsigned p = sorted[ide];
                const int s  = (int)(p >> 16);
                const int dn = (int)(p & 0xFFFFu);
                if (q4 == 0) { srcIds[e] = s; rcS[e] = 1.0f / fmaxf((float)cnt[s], 1.0f); }
                const ushort_t* sr = emb_bf + (size_t)s  * D + q4 * 16;
                const ushort_t* dr = emb_bf + (size_t)dn * D + q4 * 16;
                *(u16x8*)&prow[q4 * 16]          = *(const u16x8*)sr;
                *(u16x8*)&prow[q4 * 16 + 8]      = *(const u16x8*)(sr + 8);
                *(u16x8*)&prow[64 + q4 * 16]     = *(const u16x8*)dr;
                *(u16x8*)&prow[64 + q4 * 16 + 8] = *(const u16x8*)(dr + 8);
            } else {
                if (q4 == 0) { srcIds[e] = -1; rcS[e] = 1.0f; }
                const u16x8 z = {0,0,0,0,0,0,0,0};
                *(u16x8*)&prow[q4 * 16]          = z;
                *(u16x8*)&prow[q4 * 16 + 8]      = z;
                *(u16x8*)&prow[64 + q4 * 16]     = z;
                *(u16x8*)&prow[64 + q4 * 16 + 8] = z;
            }
        }

        // ---- GEMM1: h = relu(pair @ W1 + b1), kc-outer ----
        f32x4 acc1[4];
#pragma unroll
        for (int nt = 0; nt < 4; ++nt) {
            const float b = pb1[nt * 16 + cn];
            acc1[nt] = (f32x4){b, b, b, b};
        }
#pragma unroll
        for (int kc = 0; kc < 4; ++kc) {
            const bf16x8 a = *(const bf16x8*)&pairW[cn * PAIR_STR + kc * 32 + quad * 8];
#pragma unroll
            for (int nt = 0; nt < 4; ++nt) {
                const bf16x8 bf = *(const bf16x8*)(wpack + ((nt * 4 + kc) * 64 + ln) * 8);
                acc1[nt] = __builtin_amdgcn_mfma_f32_16x16x32_bf16(a, bf, acc1[nt], 0, 0, 0);
            }
        }
#pragma unroll
        for (int nt = 0; nt < 4; ++nt)
#pragma unroll
            for (int r = 0; r < 4; ++r)
                hW[(quad * 4 + r) * H_STR + nt * 16 + cn] = f2bf(fmaxf(acc1[nt][r], 0.f));

        // ---- GEMM2+3 fused (kc-outer) ----
        f32x4 acc2[4], accg[4];
#pragma unroll
        for (int nt = 0; nt < 4; ++nt) {
            const float b  = pb2[nt * 16 + cn];
            const float bG = bgp[nt * 16 + cn];
            acc2[nt] = (f32x4){b, b, b, b};
            accg[nt] = (f32x4){bG, bG, bG, bG};
        }
#pragma unroll
        for (int kc = 0; kc < 2; ++kc) {
            const bf16x8 a = *(const bf16x8*)&hW[cn * H_STR + kc * 32 + quad * 8];
#pragma unroll
            for (int nt = 0; nt < 4; ++nt) {
                const bf16x8 bf2 = *(const bf16x8*)(wpack + ((16 + nt * 2 + kc) * 64 + ln) * 8);
                const bf16x8 bfg = *(const bf16x8*)(wpack + ((24 + nt * 2 + kc) * 64 + ln) * 8);
                acc2[nt] = __builtin_amdgcn_mfma_f32_16x16x32_bf16(a, bf2, acc2[nt], 0, 0, 0);
                accg[nt] = __builtin_amdgcn_mfma_f32_16x16x32_bf16(a, bfg, accg[nt], 0, 0, 0);
            }
        }

        // ---- gated = interaction * sigmoid(gate_pre), in registers ----
        float g[4][4];
#pragma unroll
        for (int nt = 0; nt < 4; ++nt)
#pragma unroll
            for (int r = 0; r < 4; ++r)
                g[nt][r] = acc2[nt][r] / (1.0f + __expf(-accg[nt][r]));

        // ---- segmented reduction; flush via cross-quad butterfly ----
        {
            const int rbase = 16 * w;
            float part0 = 0.f, part1 = 0.f, part2 = 0.f, part3 = 0.f;
            int   segSrc = srcIds[rbase];
            int   segRow = 0;
#pragma unroll
            for (int i = 0; i < 16; ++i) {
                const int s = srcIds[rbase + i];          // wave-uniform
                if (s != segSrc) {
                    if (segSrc >= 0) {
                        float t0 = part0, t1 = part1, t2 = part2, t3 = part3;
                        t0 += __shfl_xor(t0, 16); t0 += __shfl_xor(t0, 32);
                        t1 += __shfl_xor(t1, 16); t1 += __shfl_xor(t1, 32);
                        t2 += __shfl_xor(t2, 16); t2 += __shfl_xor(t2, 32);
                        t3 += __shfl_xor(t3, 16); t3 += __shfl_xor(t3, 32);
                        const float tot = (quad < 2) ? (quad == 0 ? t0 : t1)
                                                     : (quad == 2 ? t2 : t3);
                        unsafeAtomicAdd(&summed[(size_t)segSrc * D + ln],
                                        tot * rcS[rbase + segRow]);
                    }
                    part0 = part1 = part2 = part3 = 0.f;
                    segSrc = s;
                    segRow = i;
                }
                if ((i >> 2) == quad) {                   // this lane holds row i
                    part0 += g[0][i & 3];
                    part1 += g[1][i & 3];
                    part2 += g[2][i & 3];
                    part3 += g[3][i & 3];
                }
            }
            if (segSrc >= 0) {
                float t0 = part0, t1 = part1, t2 = part2, t3 = part3;
                t0 += __shfl_xor(t0, 16); t0 += __shfl_xor(t0, 32);
                t1 += __shfl_xor(t1, 16); t1 += __shfl_xor(t1, 32);
                t2 += __shfl_xor(t2, 16); t2 += __shfl_xor(t2, 32);
                t3 += __shfl_xor(t3, 16); t3 += __shfl_xor(t3, 32);
                const float tot = (quad < 2) ? (quad == 0 ? t0 : t1)
                                             : (quad == 2 ? t2 : t3);
                unsafeAtomicAdd(&summed[(size_t)segSrc * D + ln],
                                tot * rcS[rbase + segRow]);
            }
        }
    }
}

extern "C" void kernel_launch(void* const* d_in, const int* in_sizes, int n_in,
                              void* d_out, int out_size, void* d_ws, size_t ws_size,
                              hipStream_t stream) {
    const float* node_emb   = (const float*)d_in[0];
    const int*   edge_index = (const int*)d_in[1];
    const float* W1 = (const float*)d_in[2];
    const float* b1 = (const float*)d_in[3];
    const float* W2 = (const float*)d_in[4];
    const float* b2 = (const float*)d_in[5];
    const float* Wg = (const float*)d_in[6];
    const float* bg = (const float*)d_in[7];

    const int N = in_sizes[0] / D;
    const int E = in_sizes[1] / 2;
    const int total_emb = N * D;

    // ws layout, EXACTLY the proven 10,034,048 B extent (N=50000, E=800000):
    // bar[16 u32] | cnt[N] | off[N] | bsum[240] | sorted[E u32] | bgp[64 f32]
    // | wpack[16384 bf16] | emb_bf[N*64 bf16]
    unsigned* bar = (unsigned*)d_ws;
    int* cnt    = (int*)d_ws + 16;
    int* off    = cnt + N;
    int* bsum   = off + N;                       // 240 ints (nsb=196 <= 240)
    unsigned* sorted = (unsigned*)(bsum + 240);
    float* bgp  = (float*)(sorted + E);
    ushort_t* wpack  = (ushort_t*)(bgp + 64);
    ushort_t* emb_bf = wpack + NFRAG * 512;

    float* summed = (float*)d_out;

    hipMemsetAsync(bar, 0, 64, stream);          // only the barrier counters

    const int ntiles = (E + TILE - 1) / TILE;
    const int nsb    = (N + 255) / 256;          // 196 (<= 240)
    uber_kernel<<<NBLK, BLOCK, 0, stream>>>(
        W1, W2, Wg, b1, b2, bg, node_emb, edge_index,
        bar, cnt, off, bsum, sorted, bgp, wpack, emb_bf,
        summed, N, E, total_emb, ntiles, nsb);
}

// Round 12
// 664.594 us; speedup vs baseline: 1.2789x; 1.2789x over previous
//
#include <hip/hip_runtime.h>

// SocialPoolingLayer: fused edge-MLP (relu(pair@W1+b1)@W2+b2, sigmoid gate, elemwise
// product) + scatter-mean by src node.
// Round 12: R10 proved the single-kernel + monotonic-counter barrier is CORRECT at
// 1024 blocks (256,4) with a normal launch; its 850us came from cache maintenance per
// poll (ACQ_REL arrival = L2 writeback, ACQUIRE poll = full L2 invalidate x ~1000
// spinners -> FETCH 840MB). R11's hipLaunchCooperativeKernel never launched (all-zero
// output). Fix the primitive, keep the structure: RELEASE arrival (one wbl2/block),
// RELAXED polls (coherent 4B read, no invalidate), one ACQUIRE agent fence after the
// spin (one buffer_inv/block). 3 barriers total (R11's phase plan): host memset zeroes
// bar+cnt; A: pack+W2Wg+bg'+cvt+zero-summed+hist; B: chunk scans; C: scatter with
// in-LDS bsum prefix; D: R9 MLP body tile-strided. Workspace = R10/R11's proven extent.

typedef unsigned short ushort_t;
typedef __attribute__((ext_vector_type(8))) short     bf16x8;   // 8 bf16 = 4 VGPRs
typedef __attribute__((ext_vector_type(8))) unsigned short u16x8;
typedef __attribute__((ext_vector_type(4))) float     f32x4;

constexpr int D        = 64;
constexpr int TILE     = 64;     // edges per tile (4 waves x 16 edges)
constexpr int BLOCK    = 256;
constexpr int NBLK     = 1024;   // 4 blocks/CU x 256 CUs, co-resident (proven in R10)
constexpr int NFRAG    = 32;     // 16 (W1) + 8 (W2) + 8 (W2@Wg) B-fragments
constexpr int SLAB_B   = 4352;   // per-wave slab: 16 rows x 272 B
constexpr int PAIR_STR = 136;    // pair row stride (bf16): 272 B
constexpr int H_STR    = 72;     // h row stride (bf16): 144 B

static __device__ __forceinline__ ushort_t f2bf(float f) {
    union { float f; unsigned int u; } v; v.f = f;
    const unsigned int r = v.u + 0x7FFFu + ((v.u >> 16) & 1u);   // RNE
    return (ushort_t)(r >> 16);
}

// Device-wide barrier: monotonic arrival counter (no reset; targets increase per use).
// RELEASE on arrival publishes this block's stores (one L2 writeback); RELAXED polls
// are plain coherent 4B reads (no cache maintenance); one ACQUIRE agent fence after
// the spin invalidates stale lines before the next phase reads (one buffer_inv).
static __device__ __forceinline__ void grid_sync(unsigned* bar, unsigned target) {
    __syncthreads();
    if (threadIdx.x == 0) {
        __hip_atomic_fetch_add(bar, 1u, __ATOMIC_RELEASE, __HIP_MEMORY_SCOPE_AGENT);
        while (__hip_atomic_load(bar, __ATOMIC_RELAXED, __HIP_MEMORY_SCOPE_AGENT) < target)
            __builtin_amdgcn_s_sleep(2);
        __builtin_amdgcn_fence(__ATOMIC_ACQUIRE, "agent");
    }
    __syncthreads();
}

__global__ __launch_bounds__(BLOCK, 4)
void uber_kernel(const float* __restrict__ W1, const float* __restrict__ W2,
                 const float* __restrict__ Wg, const float* __restrict__ pb1,
                 const float* __restrict__ pb2, const float* __restrict__ pbg,
                 const float* __restrict__ emb, const int* __restrict__ ei,
                 unsigned* __restrict__ bar, int* __restrict__ cnt,
                 int* __restrict__ off, int* __restrict__ bsum,
                 unsigned* __restrict__ sorted, float* __restrict__ bgp,
                 ushort_t* __restrict__ wpack, ushort_t* __restrict__ emb_bf,
                 float* __restrict__ summed,
                 int N, int E, int total_emb, int ntiles, int nsb)
{
    __shared__ char  slab[4][SLAB_B];    // 17408 B (phase D)
    __shared__ int   si[256];            // scan / prefix scratch (phases B, C)
    __shared__ int   srcIds[TILE];
    __shared__ float rcS[TILE];

    const int tid = threadIdx.x;
    const int bid = blockIdx.x;
    const int gid = bid * BLOCK + tid;
    constexpr int G = NBLK * BLOCK;      // 262144 threads

    // ========= phase A: pack + W2Wg + bg' + emb->bf16 + zero summed + hist ======
    // (bar and cnt are pre-zeroed by the host-side memset node.)
    // Weight fragment layout (verified R3): frag f, lane l, elem j -> W[k][n],
    // k = kc*32 + (l>>4)*8 + j, n = nt*16 + (l&15).
    for (int t = gid; t < NFRAG * 512; t += G) {
        const int f = t >> 9;
        const int l = (t >> 3) & 63;
        const int j = t & 7;
        const int k = ((f < 16) ? (f & 3) : ((f - 16) & 1)) * 32 + (l >> 4) * 8 + j;
        const int n = ((f < 16) ? (f >> 2) : (((f & 7)) >> 1)) * 16 + (l & 15);
        float v;
        if (f < 16)      v = W1[k * 64 + n];
        else if (f < 24) v = W2[k * 64 + n];
        else {                                   // (W2@Wg)[k][n]
            float s = 0.f;
            const float* wr = W2 + k * 64;
#pragma unroll 8
            for (int m = 0; m < 64; ++m) s += wr[m] * Wg[m * 64 + n];
            v = s;
        }
        wpack[t] = f2bf(v);
    }
    if (gid < 64) {                              // bg' = b2@Wg + bg (fp32)
        float s = pbg[gid];
#pragma unroll 8
        for (int m = 0; m < 64; ++m) s += pb2[m] * Wg[m * 64 + gid];
        bgp[gid] = s;
    }
    for (int i = gid; i * 8 < total_emb; i += G) {   // node_emb -> bf16
        const int base = i * 8;
        const float4 a = *(const float4*)(emb + base);
        const float4 b = *(const float4*)(emb + base + 4);
        u16x8 p;
        p[0]=f2bf(a.x); p[1]=f2bf(a.y); p[2]=f2bf(a.z); p[3]=f2bf(a.w);
        p[4]=f2bf(b.x); p[5]=f2bf(b.y); p[6]=f2bf(b.z); p[7]=f2bf(b.w);
        *(u16x8*)(emb_bf + base) = p;
    }
    for (int i = gid; i * 4 < total_emb; i += G)     // zero summed
        *(float4*)(summed + i * 4) = (float4){0.f, 0.f, 0.f, 0.f};
    for (int i = gid; i * 4 < E; i += G) {           // edge histogram by src
        const int e = i * 4;
        if (e + 3 < E) {
            const int4 v = *(const int4*)(ei + e);
            atomicAdd(&cnt[v.x], 1); atomicAdd(&cnt[v.y], 1);
            atomicAdd(&cnt[v.z], 1); atomicAdd(&cnt[v.w], 1);
        } else {
            for (int k = e; k < E; ++k) atomicAdd(&cnt[ei[k]], 1);
        }
    }

    grid_sync(bar, 1u * NBLK);

    // ========= phase B: per-256-chunk exclusive scan (nsb chunks) ===============
    if (bid < nsb) {
        const int i = bid * 256 + tid;
        const int x = (i < N) ? cnt[i] : 0;
        si[tid] = x; __syncthreads();
        for (int d = 1; d < 256; d <<= 1) {
            const int v = (tid >= d) ? si[tid - d] : 0;
            __syncthreads();
            si[tid] += v;
            __syncthreads();
        }
        if (i < N) off[i] = si[tid] - x;          // chunk-local exclusive prefix
        if (tid == 255) bsum[bid] = si[255];
    }

    grid_sync(bar, 2u * NBLK);

    // ========= phase C: scatter packed (src<<16)|dst with inline bsum prefix ====
    // Every block builds the inclusive prefix of bsum (nsb <= 256) in LDS;
    // exclusive base for chunk c is si[c-1] (0 if c==0). off[] is the cursor.
    {
        const int x = (tid < nsb) ? bsum[tid] : 0;
        si[tid] = x; __syncthreads();
        for (int d = 1; d < 256; d <<= 1) {
            const int v = (tid >= d) ? si[tid - d] : 0;
            __syncthreads();
            si[tid] += v;
            __syncthreads();
        }
    }
    for (int i = gid; i * 4 < E; i += G) {
        const int e = i * 4;
        if (e + 3 < E) {
            const int4 v  = *(const int4*)(ei + e);        // src
            const int4 d4 = *(const int4*)(ei + E + e);    // dst
            const int bx = v.x >> 8, by = v.y >> 8, bz = v.z >> 8, bw = v.w >> 8;
            sorted[(bx ? si[bx - 1] : 0) + atomicAdd(&off[v.x], 1)] =
                ((unsigned)v.x << 16) | (unsigned)d4.x;
            sorted[(by ? si[by - 1] : 0) + atomicAdd(&off[v.y], 1)] =
                ((unsigned)v.y << 16) | (unsigned)d4.y;
            sorted[(bz ? si[bz - 1] : 0) + atomicAdd(&off[v.z], 1)] =
                ((unsigned)v.z << 16) | (unsigned)d4.z;
            sorted[(bw ? si[bw - 1] : 0) + atomicAdd(&off[v.w], 1)] =
                ((unsigned)v.w << 16) | (unsigned)d4.w;
        } else {
            for (int k = e; k < E; ++k) {
                const int s = ei[k], c = s >> 8;
                sorted[(c ? si[c - 1] : 0) + atomicAdd(&off[s], 1)] =
                    ((unsigned)s << 16) | (unsigned)ei[E + k];
            }
        }
    }

    grid_sync(bar, 3u * NBLK);

    // ========= phase D: fused MFMA MLP + segmented scatter (R9 body) ============
    // Wave w owns slab[w] + srcIds/rcS rows 16w..16w+15 -> barrier-free inside.
    const int w    = tid >> 6;
    const int ln   = tid & 63;
    const int quad = ln >> 4;
    const int cn   = ln & 15;
    ushort_t* pairW = (ushort_t*)slab[w];   // [16][136]
    ushort_t* hW    = (ushort_t*)slab[w];   // [16][72] (overwrites pair after a1 reads)

    for (int tile = bid; tile < ntiles; tile += NBLK) {
        // ---- stage: one packed 4B load -> two 128B row gathers ----
        {
            const int e = tid >> 2, q4 = tid & 3;
            ushort_t* prow = (ushort_t*)&slab[e >> 4][(e & 15) * (PAIR_STR * 2)];
            const int ide = tile * TILE + e;
            if (ide < E) {
                const unsigned p = sorted[ide];
                const int s  = (int)(p >> 16);
                const int dn = (int)(p & 0xFFFFu);
                if (q4 == 0) { srcIds[e] = s; rcS[e] = 1.0f / fmaxf((float)cnt[s], 1.0f); }
                const ushort_t* sr = emb_bf + (size_t)s  * D + q4 * 16;
                const ushort_t* dr = emb_bf + (size_t)dn * D + q4 * 16;
                *(u16x8*)&prow[q4 * 16]          = *(const u16x8*)sr;
                *(u16x8*)&prow[q4 * 16 + 8]      = *(const u16x8*)(sr + 8);
                *(u16x8*)&prow[64 + q4 * 16]     = *(const u16x8*)dr;
                *(u16x8*)&prow[64 + q4 * 16 + 8] = *(const u16x8*)(dr + 8);
            } else {
                if (q4 == 0) { srcIds[e] = -1; rcS[e] = 1.0f; }
                const u16x8 z = {0,0,0,0,0,0,0,0};
                *(u16x8*)&prow[q4 * 16]          = z;
                *(u16x8*)&prow[q4 * 16 + 8]      = z;
                *(u16x8*)&prow[64 + q4 * 16]     = z;
                *(u16x8*)&prow[64 + q4 * 16 + 8] = z;
            }
        }

        // ---- GEMM1: h = relu(pair @ W1 + b1), kc-outer ----
        f32x4 acc1[4];
#pragma unroll
        for (int nt = 0; nt < 4; ++nt) {
            const float b = pb1[nt * 16 + cn];
            acc1[nt] = (f32x4){b, b, b, b};
        }
#pragma unroll
        for (int kc = 0; kc < 4; ++kc) {
            const bf16x8 a = *(const bf16x8*)&pairW[cn * PAIR_STR + kc * 32 + quad * 8];
#pragma unroll
            for (int nt = 0; nt < 4; ++nt) {
                const bf16x8 bf = *(const bf16x8*)(wpack + ((nt * 4 + kc) * 64 + ln) * 8);
                acc1[nt] = __builtin_amdgcn_mfma_f32_16x16x32_bf16(a, bf, acc1[nt], 0, 0, 0);
            }
        }
#pragma unroll
        for (int nt = 0; nt < 4; ++nt)
#pragma unroll
            for (int r = 0; r < 4; ++r)
                hW[(quad * 4 + r) * H_STR + nt * 16 + cn] = f2bf(fmaxf(acc1[nt][r], 0.f));

        // ---- GEMM2+3 fused (kc-outer) ----
        f32x4 acc2[4], accg[4];
#pragma unroll
        for (int nt = 0; nt < 4; ++nt) {
            const float b  = pb2[nt * 16 + cn];
            const float bG = bgp[nt * 16 + cn];
            acc2[nt] = (f32x4){b, b, b, b};
            accg[nt] = (f32x4){bG, bG, bG, bG};
        }
#pragma unroll
        for (int kc = 0; kc < 2; ++kc) {
            const bf16x8 a = *(const bf16x8*)&hW[cn * H_STR + kc * 32 + quad * 8];
#pragma unroll
            for (int nt = 0; nt < 4; ++nt) {
                const bf16x8 bf2 = *(const bf16x8*)(wpack + ((16 + nt * 2 + kc) * 64 + ln) * 8);
                const bf16x8 bfg = *(const bf16x8*)(wpack + ((24 + nt * 2 + kc) * 64 + ln) * 8);
                acc2[nt] = __builtin_amdgcn_mfma_f32_16x16x32_bf16(a, bf2, acc2[nt], 0, 0, 0);
                accg[nt] = __builtin_amdgcn_mfma_f32_16x16x32_bf16(a, bfg, accg[nt], 0, 0, 0);
            }
        }

        // ---- gated = interaction * sigmoid(gate_pre), in registers ----
        float g[4][4];
#pragma unroll
        for (int nt = 0; nt < 4; ++nt)
#pragma unroll
            for (int r = 0; r < 4; ++r)
                g[nt][r] = acc2[nt][r] / (1.0f + __expf(-accg[nt][r]));

        // ---- segmented reduction; flush via cross-quad butterfly ----
        {
            const int rbase = 16 * w;
            float part0 = 0.f, part1 = 0.f, part2 = 0.f, part3 = 0.f;
            int   segSrc = srcIds[rbase];
            int   segRow = 0;
#pragma unroll
            for (int i = 0; i < 16; ++i) {
                const int s = srcIds[rbase + i];          // wave-uniform
                if (s != segSrc) {
                    if (segSrc >= 0) {
                        float t0 = part0, t1 = part1, t2 = part2, t3 = part3;
                        t0 += __shfl_xor(t0, 16); t0 += __shfl_xor(t0, 32);
                        t1 += __shfl_xor(t1, 16); t1 += __shfl_xor(t1, 32);
                        t2 += __shfl_xor(t2, 16); t2 += __shfl_xor(t2, 32);
                        t3 += __shfl_xor(t3, 16); t3 += __shfl_xor(t3, 32);
                        const float tot = (quad < 2) ? (quad == 0 ? t0 : t1)
                                                     : (quad == 2 ? t2 : t3);
                        unsafeAtomicAdd(&summed[(size_t)segSrc * D + ln],
                                        tot * rcS[rbase + segRow]);
                    }
                    part0 = part1 = part2 = part3 = 0.f;
                    segSrc = s;
                    segRow = i;
                }
                if ((i >> 2) == quad) {                   // this lane holds row i
                    part0 += g[0][i & 3];
                    part1 += g[1][i & 3];
                    part2 += g[2][i & 3];
                    part3 += g[3][i & 3];
                }
            }
            if (segSrc >= 0) {
                float t0 = part0, t1 = part1, t2 = part2, t3 = part3;
                t0 += __shfl_xor(t0, 16); t0 += __shfl_xor(t0, 32);
                t1 += __shfl_xor(t1, 16); t1 += __shfl_xor(t1, 32);
                t2 += __shfl_xor(t2, 16); t2 += __shfl_xor(t2, 32);
                t3 += __shfl_xor(t3, 16); t3 += __shfl_xor(t3, 32);
                const float tot = (quad < 2) ? (quad == 0 ? t0 : t1)
                                             : (quad == 2 ? t2 : t3);
                unsafeAtomicAdd(&summed[(size_t)segSrc * D + ln],
                                tot * rcS[rbase + segRow]);
            }
        }
    }
}

extern "C" void kernel_launch(void* const* d_in, const int* in_sizes, int n_in,
                              void* d_out, int out_size, void* d_ws, size_t ws_size,
                              hipStream_t stream) {
    const float* node_emb   = (const float*)d_in[0];
    const int*   edge_index = (const int*)d_in[1];
    const float* W1 = (const float*)d_in[2];
    const float* b1 = (const float*)d_in[3];
    const float* W2 = (const float*)d_in[4];
    const float* b2 = (const float*)d_in[5];
    const float* Wg = (const float*)d_in[6];
    const float* bg = (const float*)d_in[7];

    const int N = in_sizes[0] / D;
    const int E = in_sizes[1] / 2;
    const int total_emb = N * D;

    // ws layout == R10/R11's proven extent (10,034,048 B for N=50000, E=800000):
    // bar[16 u32] | cnt[N] | off[N] | bsum[240] | sorted[E u32] | bgp[64 f32]
    // | wpack[16384 bf16] | emb_bf[N*64 bf16]
    unsigned* bar = (unsigned*)d_ws;
    int* cnt    = (int*)d_ws + 16;
    int* off    = cnt + N;
    int* bsum   = off + N;                       // 240 ints (nsb=196 <= 240)
    unsigned* sorted = (unsigned*)(bsum + 240);
    float* bgp  = (float*)(sorted + E);
    ushort_t* wpack  = (ushort_t*)(bgp + 64);
    ushort_t* emb_bf = wpack + NFRAG * 512;

    float* summed = (float*)d_out;

    // one memset node zeroes bar + cnt (phase A's histogram needs zeroed cnt)
    hipMemsetAsync(d_ws, 0, 64 + sizeof(int) * (size_t)N, stream);

    const int ntiles = (E + TILE - 1) / TILE;
    const int nsb    = (N + 255) / 256;          // 196 (<= 240)
    uber_kernel<<<NBLK, BLOCK, 0, stream>>>(
        W1, W2, Wg, b1, b2, bg, node_emb, edge_index,
        bar, cnt, off, bsum, sorted, bgp, wpack, emb_bf,
        summed, N, E, total_emb, ntiles, nsb);
}

// Round 13
// 656.509 us; speedup vs baseline: 1.2947x; 1.0123x over previous
//
#include <hip/hip_runtime.h>

// SocialPoolingLayer: fused edge-MLP (relu(pair@W1+b1)@W2+b2, sigmoid gate, elemwise
// product) + scatter-mean by src node.
// Round 13: single-kernel direction abandoned (R10/R12: FETCH 840MB is deterministic
// L2 wbinv amplification from 3072 per-block barrier fences hitting L2s shared by
// ~127 active blocks -- not fixable at HIP level). Back to R9's proven 5-node split
// (245us). New: main kernel is persistent-ish (1536 blocks = 6/CU, fully resident),
// ~8 tiles/block, with next-tile prefetch into REGISTERS (sorted word + 4x16B gather
// rows) issued right after GEMM1 consumes the current A-fragments -- the gather
// latency overlaps GEMM2/3 + flush instead of serializing. launch_bounds(256,6)
// (R7 proved (256,8)'s 64-reg unified cap spills; R8 proved (256,6) clean).

typedef unsigned short ushort_t;
typedef __attribute__((ext_vector_type(8))) short     bf16x8;   // 8 bf16 = 4 VGPRs
typedef __attribute__((ext_vector_type(8))) unsigned short u16x8;
typedef __attribute__((ext_vector_type(4))) float     f32x4;

constexpr int D        = 64;
constexpr int TILE     = 64;     // edges per tile (4 waves x 16 edges)
constexpr int BLOCK    = 256;
constexpr int NBLK_M   = 1536;   // 6 blocks/CU x 256 CUs, fully resident
constexpr int NFRAG    = 32;     // 16 (W1) + 8 (W2) + 8 (W2@Wg) B-fragments
constexpr int SLAB_B   = 4352;   // per-wave slab: 16 rows x 272 B
constexpr int PAIR_STR = 136;    // pair row stride (bf16): 272 B
constexpr int H_STR    = 72;     // h row stride (bf16): 144 B

static __device__ __forceinline__ ushort_t f2bf(float f) {
    union { float f; unsigned int u; } v; v.f = f;
    const unsigned int r = v.u + 0x7FFFu + ((v.u >> 16) & 1u);   // RNE
    return (ushort_t)(r >> 16);
}

// ---- prep: pack + W2Wg + bg' + emb->bf16 + histogram + summed-zero, one dispatch ----
// Weight fragment layout (verified R3): frag f, lane l, elem j -> W[k][n],
// k = kc*32 + (l>>4)*8 + j, n = nt*16 + (l&15).

__global__ void prep_kernel(const float* __restrict__ W1, const float* __restrict__ W2,
                            const float* __restrict__ Wg,
                            const float* __restrict__ b2, const float* __restrict__ bg,
                            const float* __restrict__ emb, const int* __restrict__ ei,
                            ushort_t* __restrict__ wpack, float* __restrict__ bgp,
                            ushort_t* __restrict__ emb_bf, int* __restrict__ cnt,
                            float* __restrict__ summed,
                            int total_emb, int cvt_blocks, int e4blocks, int E) {
    const int bid = blockIdx.x;
    if (bid < 64) {                              // 64*256 == NFRAG*512: weight packing
        const int t = bid * 256 + threadIdx.x;
        const int f = t >> 9;
        const int l = (t >> 3) & 63;
        const int j = t & 7;
        const int k = ((f < 16) ? (f & 3) : ((f - 16) & 1)) * 32 + (l >> 4) * 8 + j;
        const int n = ((f < 16) ? (f >> 2) : (((f & 7)) >> 1)) * 16 + (l & 15);
        float v;
        if (f < 16)      v = W1[k * 64 + n];
        else if (f < 24) v = W2[k * 64 + n];
        else {                                   // (W2@Wg)[k][n]
            float s = 0.f;
            const float* wr = W2 + k * 64;
#pragma unroll 8
            for (int m = 0; m < 64; ++m) s += wr[m] * Wg[m * 64 + n];
            v = s;
        }
        wpack[t] = f2bf(v);
    } else if (bid < 64 + cvt_blocks) {          // node_emb -> bf16
        const int idx  = (bid - 64) * 256 + threadIdx.x;
        const int base = idx * 8;
        if (base < total_emb) {
            const float4 a = *(const float4*)(emb + base);
            const float4 b = *(const float4*)(emb + base + 4);
            u16x8 p;
            p[0]=f2bf(a.x); p[1]=f2bf(a.y); p[2]=f2bf(a.z); p[3]=f2bf(a.w);
            p[4]=f2bf(b.x); p[5]=f2bf(b.y); p[6]=f2bf(b.z); p[7]=f2bf(b.w);
            *(u16x8*)(emb_bf + base) = p;
        }
    } else if (bid == 64 + cvt_blocks) {         // bg' = b2@Wg + bg (fp32)
        const int n = threadIdx.x;
        if (n < 64) {
            float s = bg[n];
#pragma unroll 8
            for (int m = 0; m < 64; ++m) s += b2[m] * Wg[m * 64 + n];
            bgp[n] = s;
        }
    } else if (bid < 65 + cvt_blocks + e4blocks) {   // edge histogram by src
        const int e = ((bid - 65 - cvt_blocks) * 256 + threadIdx.x) * 4;
        if (e + 3 < E) {
            const int4 v = *(const int4*)(ei + e);
            atomicAdd(&cnt[v.x], 1); atomicAdd(&cnt[v.y], 1);
            atomicAdd(&cnt[v.z], 1); atomicAdd(&cnt[v.w], 1);
        } else {
            for (int k = e; k < E; ++k) atomicAdd(&cnt[ei[k]], 1);
        }
    } else {                                     // zero summed
        const int idx  = (bid - 65 - cvt_blocks - e4blocks) * 256 + threadIdx.x;
        const int base = idx * 4;
        if (base < total_emb)
            *(float4*)(summed + base) = (float4){0.f, 0.f, 0.f, 0.f};
    }
}

// ---------------- scan: per-block exclusive offsets + block sums ----------

__global__ void scan_block(const int* __restrict__ cnt, int* __restrict__ off,
                           int* __restrict__ bsum, int N) {
    __shared__ int s[256];
    const int t = threadIdx.x, i = blockIdx.x * 256 + t;
    const int x = (i < N) ? cnt[i] : 0;
    s[t] = x; __syncthreads();
    for (int d = 1; d < 256; d <<= 1) {
        const int v = (t >= d) ? s[t - d] : 0;
        __syncthreads();
        s[t] += v;
        __syncthreads();
    }
    if (i < N) off[i] = s[t] - x;                 // block-local exclusive prefix
    if (t == 255) bsum[blockIdx.x] = s[255];
}

// scatter with inline bsum prefix (nb <= 256); off[] doubles as insertion cursor.
// Writes packed (src<<16)|dst per slot -- requires N < 65536.
__global__ void scatter_idx(const int* __restrict__ ei, int* __restrict__ off,
                            const int* __restrict__ bsum, unsigned* __restrict__ sorted,
                            int E, int nb) {
    __shared__ int pref[256];
    const int t = threadIdx.x;
    const int x = (t < nb) ? bsum[t] : 0;
    pref[t] = x; __syncthreads();
    for (int d = 1; d < 256; d <<= 1) {
        const int v = (t >= d) ? pref[t - d] : 0;
        __syncthreads();
        pref[t] += v;
        __syncthreads();
    }
    // pref[] inclusive prefix of bsum; exclusive for block b is pref[b-1] (0 if b==0)
    const int e = (blockIdx.x * blockDim.x + t) * 4;
    if (e + 3 < E) {
        const int4 v  = *(const int4*)(ei + e);        // src
        const int4 d4 = *(const int4*)(ei + E + e);    // dst
        const int bx = v.x >> 8, by = v.y >> 8, bz = v.z >> 8, bw = v.w >> 8;
        sorted[(bx ? pref[bx - 1] : 0) + atomicAdd(&off[v.x], 1)] =
            ((unsigned)v.x << 16) | (unsigned)d4.x;
        sorted[(by ? pref[by - 1] : 0) + atomicAdd(&off[v.y], 1)] =
            ((unsigned)v.y << 16) | (unsigned)d4.y;
        sorted[(bz ? pref[bz - 1] : 0) + atomicAdd(&off[v.z], 1)] =
            ((unsigned)v.z << 16) | (unsigned)d4.z;
        sorted[(bw ? pref[bw - 1] : 0) + atomicAdd(&off[v.w], 1)] =
            ((unsigned)v.w << 16) | (unsigned)d4.w;
    } else {
        for (int k = e; k < E; ++k) {
            const int s = ei[k], c = s >> 8;
            sorted[(c ? pref[c - 1] : 0) + atomicAdd(&off[s], 1)] =
                ((unsigned)s << 16) | (unsigned)ei[E + k];
        }
    }
}

// ------- fused MFMA MLP + register segmented scatter, software-pipelined ----------
// Persistent-ish: 1536 resident blocks, ~8 tiles each. Tile t+1's sorted word + four
// 16B gather rows are prefetched into registers after GEMM1 consumes tile t's
// A-fragments; the gather latency overlaps GEMM2/3 + flush. Wave w owns slab[w] +
// srcIds/rcS rows 16w..16w+15 (barrier-free; in-order per-wave DS pipe).

__global__ __launch_bounds__(BLOCK, 6)
void edge_mlp_mfma(const ushort_t* __restrict__ emb_bf,   // [N][64] bf16
                   const unsigned* __restrict__ sorted,   // packed (src<<16)|dst
                   const ushort_t* __restrict__ wpack,    // 32 packed B-frags
                   const float* __restrict__ b1, const float* __restrict__ b2,
                   const float* __restrict__ bgp,         // b2@Wg + bg
                   const int*   __restrict__ cnt,         // per-node edge counts
                   float* __restrict__ summed,            // [N][D] pre-zeroed
                   int E, int ntiles)
{
    __shared__ char  slab[4][SLAB_B];    // 17408 B: per-wave pair then h
    __shared__ int   srcIds[TILE];
    __shared__ float rcS[TILE];

    const int tid  = threadIdx.x;
    const int e    = tid >> 2, q4 = tid & 3;   // edge slot 0..63, 16-elem quarter
    const int w    = tid >> 6;
    const int ln   = tid & 63;
    const int quad = ln >> 4;
    const int cn   = ln & 15;
    ushort_t* prow  = (ushort_t*)&slab[e >> 4][(e & 15) * (PAIR_STR * 2)];
    ushort_t* pairW = (ushort_t*)slab[w];   // [16][136]
    ushort_t* hW    = (ushort_t*)slab[w];   // [16][72] (overwrites pair after a1 reads)

    const u16x8 z = {0,0,0,0,0,0,0,0};
    u16x8 r0 = z, r1 = z, r2 = z, r3 = z;   // prefetched gather rows
    int   ps  = -1;                          // prefetched src
    float prc = 1.0f;                        // prefetched 1/max(cnt,1) (q4==0 lanes)

    // ---- prefetch tile 0 ----
    {
        const int ide = blockIdx.x * TILE + e;
        if (blockIdx.x < ntiles && ide < E) {
            const unsigned p = sorted[ide];
            const int s  = (int)(p >> 16);
            const int dn = (int)(p & 0xFFFFu);
            ps = s;
            if (q4 == 0) prc = 1.0f / fmaxf((float)cnt[s], 1.0f);
            const ushort_t* sr = emb_bf + (size_t)s  * D + q4 * 16;
            const ushort_t* dr = emb_bf + (size_t)dn * D + q4 * 16;
            r0 = *(const u16x8*)sr; r1 = *(const u16x8*)(sr + 8);
            r2 = *(const u16x8*)dr; r3 = *(const u16x8*)(dr + 8);
        }
    }

    for (int tile = blockIdx.x; tile < ntiles; tile += gridDim.x) {
        // ---- stage prefetched regs -> per-wave slab (pair layout) ----
        *(u16x8*)&prow[q4 * 16]          = r0;
        *(u16x8*)&prow[q4 * 16 + 8]      = r1;
        *(u16x8*)&prow[64 + q4 * 16]     = r2;
        *(u16x8*)&prow[64 + q4 * 16 + 8] = r3;
        if (q4 == 0) { srcIds[e] = ps; rcS[e] = prc; }

        // ---- GEMM1: h = relu(pair @ W1 + b1), kc-outer ----
        f32x4 acc1[4];
#pragma unroll
        for (int nt = 0; nt < 4; ++nt) {
            const float b = b1[nt * 16 + cn];
            acc1[nt] = (f32x4){b, b, b, b};
        }
#pragma unroll
        for (int kc = 0; kc < 4; ++kc) {
            const bf16x8 a = *(const bf16x8*)&pairW[cn * PAIR_STR + kc * 32 + quad * 8];
#pragma unroll
            for (int nt = 0; nt < 4; ++nt) {
                const bf16x8 bf = *(const bf16x8*)(wpack + ((nt * 4 + kc) * 64 + ln) * 8);
                acc1[nt] = __builtin_amdgcn_mfma_f32_16x16x32_bf16(a, bf, acc1[nt], 0, 0, 0);
            }
        }

        // ---- prefetch tile + gridDim.x (overlaps GEMM2/3 + flush) ----
        {
            const int t2  = tile + (int)gridDim.x;
            const int ide = t2 * TILE + e;
            if (t2 < ntiles && ide < E) {
                const unsigned p = sorted[ide];
                const int s  = (int)(p >> 16);
                const int dn = (int)(p & 0xFFFFu);
                ps = s;
                if (q4 == 0) prc = 1.0f / fmaxf((float)cnt[s], 1.0f);
                const ushort_t* sr = emb_bf + (size_t)s  * D + q4 * 16;
                const ushort_t* dr = emb_bf + (size_t)dn * D + q4 * 16;
                r0 = *(const u16x8*)sr; r1 = *(const u16x8*)(sr + 8);
                r2 = *(const u16x8*)dr; r3 = *(const u16x8*)(dr + 8);
            } else {
                ps = -1; prc = 1.0f;
                r0 = z; r1 = z; r2 = z; r3 = z;
            }
        }

        // ---- h -> LDS (bf16) ----
#pragma unroll
        for (int nt = 0; nt < 4; ++nt)
#pragma unroll
            for (int r = 0; r < 4; ++r)
                hW[(quad * 4 + r) * H_STR + nt * 16 + cn] = f2bf(fmaxf(acc1[nt][r], 0.f));

        // ---- GEMM2+3 fused (kc-outer) ----
        f32x4 acc2[4], accg[4];
#pragma unroll
        for (int nt = 0; nt < 4; ++nt) {
            const float b  = b2 [nt * 16 + cn];
            const float bG = bgp[nt * 16 + cn];
            acc2[nt] = (f32x4){b, b, b, b};
            accg[nt] = (f32x4){bG, bG, bG, bG};
        }
#pragma unroll
        for (int kc = 0; kc < 2; ++kc) {
            const bf16x8 a = *(const bf16x8*)&hW[cn * H_STR + kc * 32 + quad * 8];
#pragma unroll
            for (int nt = 0; nt < 4; ++nt) {
                const bf16x8 bf2 = *(const bf16x8*)(wpack + ((16 + nt * 2 + kc) * 64 + ln) * 8);
                const bf16x8 bfg = *(const bf16x8*)(wpack + ((24 + nt * 2 + kc) * 64 + ln) * 8);
                acc2[nt] = __builtin_amdgcn_mfma_f32_16x16x32_bf16(a, bf2, acc2[nt], 0, 0, 0);
                accg[nt] = __builtin_amdgcn_mfma_f32_16x16x32_bf16(a, bfg, accg[nt], 0, 0, 0);
            }
        }

        // ---- gated = interaction * sigmoid(gate_pre), in registers ----
        float g[4][4];
#pragma unroll
        for (int nt = 0; nt < 4; ++nt)
#pragma unroll
            for (int r = 0; r < 4; ++r)
                g[nt][r] = acc2[nt][r] / (1.0f + __expf(-accg[nt][r]));

        // ---- segmented reduction; flush via cross-quad butterfly ----
        {
            const int rbase = 16 * w;
            float part0 = 0.f, part1 = 0.f, part2 = 0.f, part3 = 0.f;
            int   segSrc = srcIds[rbase];
            int   segRow = 0;
#pragma unroll
            for (int i = 0; i < 16; ++i) {
                const int s = srcIds[rbase + i];          // wave-uniform
                if (s != segSrc) {
                    if (segSrc >= 0) {
                        float t0 = part0, t1 = part1, t2 = part2, t3 = part3;
                        t0 += __shfl_xor(t0, 16); t0 += __shfl_xor(t0, 32);
                        t1 += __shfl_xor(t1, 16); t1 += __shfl_xor(t1, 32);
                        t2 += __shfl_xor(t2, 16); t2 += __shfl_xor(t2, 32);
                        t3 += __shfl_xor(t3, 16); t3 += __shfl_xor(t3, 32);
                        const float tot = (quad < 2) ? (quad == 0 ? t0 : t1)
                                                     : (quad == 2 ? t2 : t3);
                        unsafeAtomicAdd(&summed[(size_t)segSrc * D + ln],
                                        tot * rcS[rbase + segRow]);
                    }
                    part0 = part1 = part2 = part3 = 0.f;
                    segSrc = s;
                    segRow = i;
                }
                if ((i >> 2) == quad) {                   // this lane holds row i
                    part0 += g[0][i & 3];
                    part1 += g[1][i & 3];
                    part2 += g[2][i & 3];
                    part3 += g[3][i & 3];
                }
            }
            if (segSrc >= 0) {
                float t0 = part0, t1 = part1, t2 = part2, t3 = part3;
                t0 += __shfl_xor(t0, 16); t0 += __shfl_xor(t0, 32);
                t1 += __shfl_xor(t1, 16); t1 += __shfl_xor(t1, 32);
                t2 += __shfl_xor(t2, 16); t2 += __shfl_xor(t2, 32);
                t3 += __shfl_xor(t3, 16); t3 += __shfl_xor(t3, 32);
                const float tot = (quad < 2) ? (quad == 0 ? t0 : t1)
                                             : (quad == 2 ? t2 : t3);
                unsafeAtomicAdd(&summed[(size_t)segSrc * D + ln],
                                tot * rcS[rbase + segRow]);
            }
        }
    }
}

extern "C" void kernel_launch(void* const* d_in, const int* in_sizes, int n_in,
                              void* d_out, int out_size, void* d_ws, size_t ws_size,
                              hipStream_t stream) {
    const float* node_emb   = (const float*)d_in[0];
    const int*   edge_index = (const int*)d_in[1];
    const float* W1 = (const float*)d_in[2];
    const float* b1 = (const float*)d_in[3];
    const float* W2 = (const float*)d_in[4];
    const float* b2 = (const float*)d_in[5];
    const float* Wg = (const float*)d_in[6];
    const float* bg = (const float*)d_in[7];

    const int N = in_sizes[0] / D;
    const int E = in_sizes[1] / 2;
    const int total_emb = N * D;

    // ws layout == R9's proven extent (10,034,048 B for N=50000, E=800000):
    // cnt[N] | off[N] | bsum[256] | sorted[E u32] | bgp[64 f32] | wpack[16K bf16] | emb_bf
    int* cnt    = (int*)d_ws;
    int* off    = cnt + N;
    int* bsum   = off + N;
    unsigned* sorted = (unsigned*)(bsum + 256);
    float* bgp  = (float*)(sorted + E);
    ushort_t* wpack  = (ushort_t*)(bgp + 64);
    ushort_t* emb_bf = wpack + NFRAG * 512;

    float* summed = (float*)d_out;

    hipMemsetAsync(cnt, 0, sizeof(int) * (size_t)N, stream);   // precedes prep's hist

    const int cvt_blocks = (total_emb / 8 + 255) / 256;
    const int e4blocks   = ((E + 3) / 4 + 255) / 256;
    const int zblocks    = (total_emb / 4 + 255) / 256;
    prep_kernel<<<64 + cvt_blocks + 1 + e4blocks + zblocks, 256, 0, stream>>>(
        W1, W2, Wg, b2, bg, node_emb, edge_index,
        wpack, bgp, emb_bf, cnt, summed, total_emb, cvt_blocks, e4blocks, E);

    const int nblocks = (N + 255) / 256;   // 196 (must be <= 256 for inline prefix)
    scan_block <<<nblocks, 256, 0, stream>>>(cnt, off, bsum, N);
    scatter_idx<<<e4blocks, 256, 0, stream>>>(edge_index, off, bsum, sorted, E, nblocks);

    const int ntiles = (E + TILE - 1) / TILE;
    edge_mlp_mfma<<<NBLK_M, BLOCK, 0, stream>>>(emb_bf, sorted, wpack,
                                                b1, b2, bgp, cnt, summed, E, ntiles);
}